// Round 4
// baseline (107.687 us; speedup 1.0000x reference)
//
#include <hip/hip_runtime.h>

#define NB 4096
#define T_FRAMES 8192
#define T_TOKENS 2048
#define NTHREADS 256
#define TPT (T_TOKENS / NTHREADS)   // 8 tokens per thread
#define NWAVES (NTHREADS / 64)      // 4
#define MAX_DUR_M1 7                // durations in [0, 8)

__global__ __launch_bounds__(NTHREADS, 8) void avg_by_dur_kernel(
    const float* __restrict__ frame_scalar,
    const int*   __restrict__ frame_len,
    const int*   __restrict__ duration,
    const int*   __restrict__ duration_len,
    float*       __restrict__ out)
{
    __shared__ int s_wsum[NWAVES];        // 16 B: cross-wave scan exchange

    const int row  = blockIdx.x;
    const int t    = threadIdx.x;
    const int lane = t & 63;
    const int wid  = t >> 6;

    const int L    = frame_len[row];
    const int dlen = duration_len[row];

    // ---- output 1 early (independent of everything else)
    if (t == 0) {
        out[(size_t)NB * T_TOKENS + row] = (float)dlen;
    }

    // ---- durations for this thread's 8 tokens (skip fully-invalid threads:
    // their durations only influence tokens >= dlen, which output 0 anyway)
    int d[TPT] = {0, 0, 0, 0, 0, 0, 0, 0};
    if (t * TPT < dlen) {
        const int4* drow = reinterpret_cast<const int4*>(duration + (size_t)row * T_TOKENS) + t * 2;
        int4 a = drow[0];
        int4 b = drow[1];
        d[0] = a.x; d[1] = a.y; d[2] = a.z; d[3] = a.w;
        d[4] = b.x; d[5] = b.y; d[6] = b.z; d[7] = b.w;
    }
    int incl[TPT];
    int run = 0;
    #pragma unroll
    for (int k = 0; k < TPT; ++k) {
        int v = d[k] > 0 ? d[k] : 0;
        run += v;
        incl[k] = run;
    }

    // ---- wave-level inclusive scan of per-thread sums (no barriers)
    int x = run;
    #pragma unroll
    for (int off = 1; off < 64; off <<= 1) {
        int y = __shfl_up(x, off, 64);
        if (lane >= off) x += y;
    }
    if (lane == 63) s_wsum[wid] = x;

    // ---- single barrier: publish wave sums
    __syncthreads();

    int wbase = 0;
    #pragma unroll
    for (int w = 0; w < NWAVES; ++w)
        if (w < wid) wbase += s_wsum[w];
    const int base = wbase + (x - run);   // exclusive prefix over all prior tokens

    // ---- per-token segment means, frames read directly from global.
    // Thread's range [base, base+run) is contiguous; adjacent threads adjoin,
    // so every cache line in [0, min(csum_total, L)) is consumed exactly once.
    const float* frow = frame_scalar + (size_t)row * T_FRAMES;
    float outv[TPT];
    int start = base < L ? base : L;
    #pragma unroll
    for (int k = 0; k < TPT; ++k) {
        int e = base + incl[k];
        if (e > L) e = L;
        const int j = t * TPT + k;
        const int len = e - start;
        float r = 0.0f;
        if (len > 0 && j < dlen) {
            float s = 0.0f;
            #pragma unroll
            for (int q = 0; q < MAX_DUR_M1; ++q) {
                const int idx = start + q;
                if (idx < e) s += frow[idx];   // exec-mask predicated load
            }
            r = s / (float)len;
        }
        outv[k] = r;
        start = e;
    }

    // ---- coalesced store: two float4 per thread
    float4* orow = reinterpret_cast<float4*>(out + (size_t)row * T_TOKENS) + t * 2;
    orow[0] = make_float4(outv[0], outv[1], outv[2], outv[3]);
    orow[1] = make_float4(outv[4], outv[5], outv[6], outv[7]);
}

extern "C" void kernel_launch(void* const* d_in, const int* in_sizes, int n_in,
                              void* d_out, int out_size, void* d_ws, size_t ws_size,
                              hipStream_t stream) {
    const float* frame_scalar     = (const float*)d_in[0];
    const int*   frame_scalar_len = (const int*)d_in[1];
    const int*   duration         = (const int*)d_in[2];
    const int*   duration_len     = (const int*)d_in[3];
    float* out = (float*)d_out;

    avg_by_dur_kernel<<<NB, NTHREADS, 0, stream>>>(
        frame_scalar, frame_scalar_len, duration, duration_len, out);
}

// Round 5
// 39.104 us; speedup vs baseline: 2.7538x; 2.7538x over previous
//
#include <hip/hip_runtime.h>

#define NB 4096
#define T_FRAMES 8192
#define T_TOKENS 2048
#define MAX_DUR_M1 7              // durations in [0, 8)

// Kernel A geometry: one block per row, 256 threads, 8 tokens/thread
#define ATHREADS 256
#define A_TPT (T_TOKENS / ATHREADS)       // 8
#define NWAVES (ATHREADS / 64)            // 4

// Kernel B geometry: one wave-job per 128 tokens
#define SEGS 16                           // wave-jobs per row
#define TOK_PER_JOB (T_TOKENS / SEGS)     // 128
#define B_TPT 2                           // tokens per lane
#define JOBS_PER_BLOCK 4                  // 4 waves = 256 threads
#define BTHREADS 256
#define SLOT_FLOATS 904                   // 128*7 + float4 alignment slack
#define NBLOCKS_B (NB * SEGS / JOBS_PER_BLOCK)

__device__ __forceinline__ void load_lds16(const float4* g, float4* l) {
    __builtin_amdgcn_global_load_lds(
        (const __attribute__((address_space(1))) void*)g,
        (__attribute__((address_space(3))) void*)l,
        16, 0, 0);
}

// ---------------- Kernel A: per-row duration scan -> 16 boundary cumsums ----
__global__ __launch_bounds__(ATHREADS) void scan_kernel(
    const int* __restrict__ duration,
    const int* __restrict__ duration_len,
    int*       __restrict__ bounds,     // [NB][SEGS] raw exclusive cumsum at seg starts
    float*     __restrict__ out)
{
    __shared__ int s_wsum[NWAVES];

    const int row  = blockIdx.x;
    const int t    = threadIdx.x;
    const int lane = t & 63;
    const int wid  = t >> 6;
    const int dlen = duration_len[row];

    if (t == 0) out[(size_t)NB * T_TOKENS + row] = (float)dlen;  // output 1

    // durations for tokens [8t, 8t+8); tokens >= dlen only feed boundaries
    // that kernel B never uses (their jobs early-out), so zero them.
    int run = 0;
    if (t * A_TPT < dlen) {
        const int4* drow = reinterpret_cast<const int4*>(duration + (size_t)row * T_TOKENS) + t * 2;
        int4 a = drow[0];
        int4 b = drow[1];
        run = max(a.x,0)+max(a.y,0)+max(a.z,0)+max(a.w,0)
            + max(b.x,0)+max(b.y,0)+max(b.z,0)+max(b.w,0);
    }

    int x = run;
    #pragma unroll
    for (int off = 1; off < 64; off <<= 1) {
        int y = __shfl_up(x, off, 64);
        if (lane >= off) x += y;
    }
    if (lane == 63) s_wsum[wid] = x;
    __syncthreads();

    int wbase = 0;
    #pragma unroll
    for (int w = 0; w < NWAVES; ++w)
        if (w < wid) wbase += s_wsum[w];
    const int base = wbase + (x - run);   // exclusive cumsum before token 8t

    if ((t & 15) == 0) bounds[row * SEGS + (t >> 4)] = base;  // t*8 = 128*(t/16)
}

// ---------------- Kernel B: one independent wave-job per 128 tokens ---------
__global__ __launch_bounds__(BTHREADS) void avg_kernel(
    const float* __restrict__ frame_scalar,
    const int*   __restrict__ frame_len,
    const int*   __restrict__ duration,
    const int*   __restrict__ duration_len,
    const int*   __restrict__ bounds,
    float*       __restrict__ out)
{
    __shared__ float s_frame[JOBS_PER_BLOCK][SLOT_FLOATS];

    const int t    = threadIdx.x;
    const int lane = t & 63;
    const int wid  = t >> 6;
    const int job  = blockIdx.x * JOBS_PER_BLOCK + wid;
    const int row  = job >> 4;           // /SEGS
    const int seg  = job & (SEGS - 1);
    const int T0   = seg * TOK_PER_JOB;

    const int dlen = duration_len[row];
    float2* ostore = reinterpret_cast<float2*>(out + (size_t)row * T_TOKENS + T0) + lane;

    if (T0 >= dlen) {                    // whole job past duration_len -> zeros
        *ostore = make_float2(0.0f, 0.0f);
        return;
    }

    const int L  = frame_len[row];
    const int c0 = bounds[row * SEGS + seg];

    // ---- this lane's 2 durations
    const int2 dd = *(reinterpret_cast<const int2*>(duration + (size_t)row * T_TOKENS + T0) + lane);
    const int j0 = T0 + 2 * lane;
    int v0 = (j0     < dlen) ? max(dd.x, 0) : 0;
    int v1 = (j0 + 1 < dlen) ? max(dd.y, 0) : 0;
    const int i0  = v0;
    const int run = v0 + v1;

    // ---- wave inclusive scan (no barriers anywhere in this kernel)
    int x = run;
    #pragma unroll
    for (int off = 1; off < 64; off <<= 1) {
        int y = __shfl_up(x, off, 64);
        if (lane >= off) x += y;
    }
    const int base   = c0 + (x - run);
    const int wtotal = __shfl(x, 63);

    // ---- stage exactly this job's frame span into this wave's LDS slot
    const int rs  = min(c0, L);
    const int re  = min(c0 + wtotal, L);
    const int rs4 = rs >> 2;
    const int n4  = ((re + 3) >> 2) - rs4;          // <= 226 float4
    const float4* g4 = reinterpret_cast<const float4*>(frame_scalar + (size_t)row * T_FRAMES) + rs4;
    float4* l4 = reinterpret_cast<float4*>(&s_frame[wid][0]);
    const int rounds = (n4 + 63) >> 6;              // wave-uniform trip count
    for (int i = 0; i < rounds; ++i) {
        const int p = i * 64 + lane;
        if (p < n4) load_lds16(g4 + p, l4 + p);
    }
    asm volatile("s_waitcnt vmcnt(0)" ::: "memory"); // own loads only; no block barrier

    // ---- two segment means from LDS
    const int off0 = rs4 << 2;                       // slot-relative origin
    const float* sl = &s_frame[wid][0];
    float o[B_TPT];
    int s = min(base, L);
    int eends[B_TPT] = { min(base + i0, L), min(base + run, L) };
    #pragma unroll
    for (int k = 0; k < B_TPT; ++k) {
        const int e = eends[k];
        const int len = e - s;
        float r = 0.0f;
        if (len > 0 && (j0 + k) < dlen) {
            float acc = 0.0f;
            #pragma unroll
            for (int q = 0; q < MAX_DUR_M1; ++q) {
                const int idx = s + q;
                if (idx < e) acc += sl[idx - off0];
            }
            r = acc / (float)len;
        }
        o[k] = r;
        s = e;
    }

    *ostore = make_float2(o[0], o[1]);
}

extern "C" void kernel_launch(void* const* d_in, const int* in_sizes, int n_in,
                              void* d_out, int out_size, void* d_ws, size_t ws_size,
                              hipStream_t stream) {
    const float* frame_scalar     = (const float*)d_in[0];
    const int*   frame_scalar_len = (const int*)d_in[1];
    const int*   duration         = (const int*)d_in[2];
    const int*   duration_len     = (const int*)d_in[3];
    float* out    = (float*)d_out;
    int*   bounds = (int*)d_ws;          // NB*SEGS*4 = 256 KB

    scan_kernel<<<NB, ATHREADS, 0, stream>>>(duration, duration_len, bounds, out);
    avg_kernel<<<NBLOCKS_B, BTHREADS, 0, stream>>>(
        frame_scalar, frame_scalar_len, duration, duration_len, bounds, out);
}

// Round 6
// 27.761 us; speedup vs baseline: 3.8791x; 1.4086x over previous
//
#include <hip/hip_runtime.h>

#define NB 4096
#define T_FRAMES 8192
#define T_TOKENS 2048
#define NTHREADS 512
#define TPT (T_TOKENS / NTHREADS)   // 4 tokens per thread
#define NWAVES (NTHREADS / 64)      // 8
#define MAX_DUR_M1 7                // durations in [0, 8)

__device__ __forceinline__ void load_lds16(const float4* g, float4* l) {
    __builtin_amdgcn_global_load_lds(
        (const __attribute__((address_space(1))) void*)g,
        (__attribute__((address_space(3))) void*)l,
        16, 0, 0);
}

__global__ __launch_bounds__(NTHREADS, 8) void avg_by_dur_kernel(
    const float* __restrict__ frame_scalar,
    const int*   __restrict__ frame_len,
    const int*   __restrict__ duration,
    const int*   __restrict__ duration_len,
    float*       __restrict__ out)
{
    __shared__ float s_frame[T_FRAMES];   // 32 KB staged frame prefix
    __shared__ int   s_wsum[NWAVES];

    const int row  = blockIdx.x;
    const int t    = threadIdx.x;
    const int lane = t & 63;
    const int wid  = t >> 6;

    const int L    = frame_len[row];
    const int dlen = duration_len[row];

    // ---- output 1 early (independent of everything else)
    if (t == 0) {
        out[(size_t)NB * T_TOKENS + row] = (float)dlen;
    }

    // ---- durations for this thread's 4 tokens (one int4; skip if all >= dlen)
    int d[TPT] = {0, 0, 0, 0};
    if (t * TPT < dlen) {
        const int4 a = reinterpret_cast<const int4*>(duration + (size_t)row * T_TOKENS)[t];
        d[0] = a.x; d[1] = a.y; d[2] = a.z; d[3] = a.w;
    }
    int incl[TPT];
    int run = 0;
    #pragma unroll
    for (int k = 0; k < TPT; ++k) {
        int v = d[k] > 0 ? d[k] : 0;
        run += v;
        incl[k] = run;
    }

    // ---- wave-level inclusive scan of per-thread sums
    int x = run;
    #pragma unroll
    for (int off = 1; off < 64; off <<= 1) {
        int y = __shfl_up(x, off, 64);
        if (lane >= off) x += y;
    }
    if (lane == 63) s_wsum[wid] = x;

    // ---- barrier 1: publish wave sums
    __syncthreads();

    int wbase = 0;
    int total = 0;
    #pragma unroll
    for (int w = 0; w < NWAVES; ++w) {
        const int s = s_wsum[w];
        total += s;
        if (w < wid) wbase += s;
    }
    const int base = wbase + (x - run);   // exclusive prefix over all prior tokens

    // Exact frame span touched by valid tokens: [0, min(total_csum, L)).
    const int needed  = total < L ? total : L;
    const int needed4 = (needed + 3) >> 2;

    // ---- async global->LDS staging of exactly the needed frame prefix
    const float4* frow = reinterpret_cast<const float4*>(frame_scalar + (size_t)row * T_FRAMES);
    float4* lrow = reinterpret_cast<float4*>(s_frame);
    #pragma unroll
    for (int i = 0; i < T_FRAMES / 4 / NTHREADS; ++i) {   // 4 predicated 16B loads
        const int p = t + i * NTHREADS;
        if (p < needed4) load_lds16(frow + p, lrow + p);
    }

    // ---- barrier 2: drains global_load_lds (compiler emits vmcnt(0) before s_barrier)
    __syncthreads();

    // ---- per-token segment means from LDS
    float outv[TPT];
    int start = base < L ? base : L;
    #pragma unroll
    for (int k = 0; k < TPT; ++k) {
        int e = base + incl[k];
        if (e > L) e = L;
        const int j = t * TPT + k;
        const int len = e - start;
        float r = 0.0f;
        if (len > 0 && j < dlen) {
            float s = 0.0f;
            #pragma unroll
            for (int q = 0; q < MAX_DUR_M1; ++q) {
                const int idx = start + q;
                const float v = s_frame[idx < e ? idx : start];
                if (idx < e) s += v;
            }
            r = s / (float)len;
        }
        outv[k] = r;
        start = e;
    }

    // ---- coalesced store: one float4 per thread
    reinterpret_cast<float4*>(out + (size_t)row * T_TOKENS)[t] =
        make_float4(outv[0], outv[1], outv[2], outv[3]);
}

extern "C" void kernel_launch(void* const* d_in, const int* in_sizes, int n_in,
                              void* d_out, int out_size, void* d_ws, size_t ws_size,
                              hipStream_t stream) {
    const float* frame_scalar     = (const float*)d_in[0];
    const int*   frame_scalar_len = (const int*)d_in[1];
    const int*   duration         = (const int*)d_in[2];
    const int*   duration_len     = (const int*)d_in[3];
    float* out = (float*)d_out;

    avg_by_dur_kernel<<<NB, NTHREADS, 0, stream>>>(
        frame_scalar, frame_scalar_len, duration, duration_len, out);
}